// Round 2
// baseline (968.341 us; speedup 1.0000x reference)
//
#include <hip/hip_runtime.h>
#include <hip/hip_bf16.h>
#include <cstdint>

#define TEMPF 3.0f
#define EPSF 1e-5f

// ---------- type helpers (f32 <-> bf16 staging) ----------
static __device__ __forceinline__ float bf2f(unsigned short u){
  union { unsigned u32; float f; } x; x.u32 = ((unsigned)u) << 16; return x.f;
}
static __device__ __forceinline__ unsigned short f2bf(float f){
  unsigned u = __float_as_uint(f);
  unsigned r = (u + 0x7fffu + ((u >> 16) & 1u)) >> 16;   // RNE
  return (unsigned short)r;
}
static __device__ __forceinline__ float ld1(const float* p){ return *p; }
static __device__ __forceinline__ float ld1(const __hip_bfloat16* p){
  return bf2f(*(const unsigned short*)p);
}
static __device__ __forceinline__ float4 ld4(const float* p){ return *(const float4*)p; }
static __device__ __forceinline__ float4 ld4(const __hip_bfloat16* p){
  ushort4 u = *(const ushort4*)p;
  return make_float4(bf2f(u.x), bf2f(u.y), bf2f(u.z), bf2f(u.w));
}
static __device__ __forceinline__ void st4(float* p, float4 v){ *(float4*)p = v; }
static __device__ __forceinline__ void st4(__hip_bfloat16* p, float4 v){
  *(ushort4*)p = make_ushort4(f2bf(v.x), f2bf(v.y), f2bf(v.z), f2bf(v.w));
}

// ---------- ordered-uint float encoding for atomic max ----------
static __device__ __forceinline__ unsigned fkey(float f){
  unsigned u = __float_as_uint(f);
  return (u & 0x80000000u) ? ~u : (u | 0x80000000u);
}
static __device__ __forceinline__ float fdec(unsigned k){
  return (k & 0x80000000u) ? __uint_as_float(k ^ 0x80000000u) : __uint_as_float(~k);
}

__device__ __forceinline__ float blockMax256(float v){
  __shared__ float red[4];
  #pragma unroll
  for(int off = 32; off; off >>= 1) v = fmaxf(v, __shfl_down(v, off));
  __syncthreads();
  if((threadIdx.x & 63) == 0) red[threadIdx.x >> 6] = v;
  __syncthreads();
  return fmaxf(fmaxf(red[0], red[1]), fmaxf(red[2], red[3]));
}
__device__ __forceinline__ float blockSum256(float v){
  __shared__ float red2[4];
  #pragma unroll
  for(int off = 32; off; off >>= 1) v += __shfl_down(v, off);
  __syncthreads();
  if((threadIdx.x & 63) == 0) red2[threadIdx.x >> 6] = v;
  __syncthreads();
  return red2[0] + red2[1] + red2[2] + red2[3];
}

// ---------- mask dtype detection (bool may arrive as u8 / i32 / f32) ----------
__global__ void detect_k(const unsigned* __restrict__ m, int* __restrict__ flag){
  __shared__ int sa, sb;
  int tid = threadIdx.x;
  if(tid == 0){ sa = 0; sb = 0; }
  __syncthreads();
  int a = 0, b2 = 0;
  for(int i = tid; i < 1024; i += 256){     // first 4096 bytes: safe in all layouts
    unsigned w = m[i];
    if(w != 0u && w != 1u) a = 1;                    // not pure {0,1} int32
    if(w != 0u && w != 0x3f800000u) b2 = 1;          // not pure {0,1.0f} f32
  }
  if(a)  atomicOr(&sa, 1);
  if(b2) atomicOr(&sb, 1);
  __syncthreads();
  if(tid == 0) *flag = (sa == 0) ? 0 : ((sb == 0) ? 1 : 2);  // 0=int32 1=f32 2=u8
}

__global__ void zero_k(unsigned* a, unsigned* b){
  int i = blockIdx.x * 256 + threadIdx.x;
  if(i < 4096){ a[i] = 0u; b[i] = 0u; }
}

// ---------- row max over 1024-wide rows ----------
__global__ __launch_bounds__(256) void rowmax_k(const float* __restrict__ x,
                                                float* __restrict__ rmax){
  int row = blockIdx.x;                       // 0..4095  (b*1024+q)
  float4 v = *(const float4*)(x + (size_t)row * 1024 + threadIdx.x * 4);
  float m = fmaxf(fmaxf(v.x, v.y), fmaxf(v.z, v.w));
  m = blockMax256(m);
  if(threadIdx.x == 0) rmax[row] = m;
}

// ---------- col max via ordered-uint atomics ----------
__global__ __launch_bounds__(256) void colmax_k(const float* __restrict__ x,
                                                unsigned* __restrict__ cbits){
  int blk = blockIdx.x;                       // B*32 blocks, 32 rows each
  int b = blk >> 5, rg = blk & 31;
  const float* base = x + (size_t)b * 1024 * 1024 + (size_t)rg * 32 * 1024;
  int col = threadIdx.x * 4;
  float4 m = make_float4(-1e30f, -1e30f, -1e30f, -1e30f);
  for(int r = 0; r < 32; ++r){
    float4 v = *(const float4*)(base + r * 1024 + col);
    m.x = fmaxf(m.x, v.x); m.y = fmaxf(m.y, v.y);
    m.z = fmaxf(m.z, v.z); m.w = fmaxf(m.w, v.w);
  }
  unsigned* cb = cbits + (b << 10) + col;
  atomicMax(cb + 0, fkey(m.x)); atomicMax(cb + 1, fkey(m.y));
  atomicMax(cb + 2, fkey(m.z)); atomicMax(cb + 3, fkey(m.w));
}

// ---------- mutual matching elementwise: c^3 / ((rmax+eps)(cmax+eps)) ----------
__global__ __launch_bounds__(256) void mmapply_k(const float* __restrict__ x,
    const float* __restrict__ rmax, const unsigned* __restrict__ cbits,
    float* __restrict__ out){
  int idx4 = blockIdx.x * 256 + threadIdx.x;  // over 1M float4
  int b = idx4 >> 18;
  int rem = idx4 & 262143;
  int q = rem >> 8;
  int k = (rem & 255) * 4;
  float4 v = ((const float4*)x)[idx4];
  float ra = rmax[(b << 10) + q] + EPSF;
  const unsigned* cb = cbits + (b << 10) + k;
  float4 o;
  o.x = v.x * v.x * v.x / (ra * (fdec(cb[0]) + EPSF));
  o.y = v.y * v.y * v.y / (ra * (fdec(cb[1]) + EPSF));
  o.z = v.z * v.z * v.z / (ra * (fdec(cb[2]) + EPSF));
  o.w = v.w * v.w * v.w / (ra * (fdec(cb[3]) + EPSF));
  ((float4*)out)[idx4] = o;
}

// ---------- fused CenterPivotConv4d layer (ONE batch): convHW(wA)+convSS(wB)+bias, relu ----------
// block = one (h,w); 256 threads own the 1024 (hs,ws) positions (4 each).
// in/out layouts: [CI,32,32,1024] / [CO,32,32,1024] (batch pre-offset by host).
template<int CI, int CO, bool ACCUM, typename TI, typename TO>
__global__ __launch_bounds__(256) void conv_k(
    const TI* __restrict__ in, TO* __restrict__ out,
    const float* __restrict__ wA, const float* __restrict__ bA,
    const float* __restrict__ wB, const float* __restrict__ bB){
  __shared__ float P[34 * 34];
  const int tid = threadIdx.x;
  const int blk = blockIdx.x;                 // 0..1023
  const int w = blk & 31, h = blk >> 5;
  const int s1 = (tid * 4) >> 5, s2 = (tid * 4) & 31;

  float acc[CO][4];
  #pragma unroll
  for(int co = 0; co < CO; ++co){
    float bv = bA[co] + bB[co];
    acc[co][0] = bv; acc[co][1] = bv; acc[co][2] = bv; acc[co][3] = bv;
  }

  for(int ci = 0; ci < CI; ++ci){
    const TI* cin = in + (size_t)((ci * 32 + h) * 32 + w) * 1024;
    __syncthreads();  // protect previous iteration's P readers
    for(int i = tid; i < 34 * 34; i += 256){
      int r = i / 34, c = i % 34;
      int a1 = r - 1, a2 = c - 1;
      float val = 0.f;
      if((unsigned)a1 < 32u && (unsigned)a2 < 32u) val = ld1(cin + a1 * 32 + a2);
      P[i] = val;
    }
    // query-conv neighbor rows (global, zero-padded SAME)
    float4 qv[9];
    #pragma unroll
    for(int dh = 0; dh < 3; ++dh){
      #pragma unroll
      for(int dw = 0; dw < 3; ++dw){
        int hh = h + dh - 1, ww = w + dw - 1;
        float4 vv = make_float4(0.f, 0.f, 0.f, 0.f);
        if((unsigned)hh < 32u && (unsigned)ww < 32u)
          vv = ld4(in + (size_t)((ci * 32 + hh) * 32 + ww) * 1024 + tid * 4);
        qv[dh * 3 + dw] = vv;
      }
    }
    __syncthreads();
    float pr[3][6];
    #pragma unroll
    for(int k1 = 0; k1 < 3; ++k1)
      #pragma unroll
      for(int c6 = 0; c6 < 6; ++c6)
        pr[k1][c6] = P[(s1 + k1) * 34 + s2 + c6];

    #pragma unroll
    for(int co = 0; co < CO; ++co){
      const float* wa = wA + (co * CI + ci) * 9;
      const float* wb = wB + (co * CI + ci) * 9;
      #pragma unroll
      for(int t = 0; t < 9; ++t){
        float wv = wa[t];
        float4 vv = qv[t];
        acc[co][0] += wv * vv.x; acc[co][1] += wv * vv.y;
        acc[co][2] += wv * vv.z; acc[co][3] += wv * vv.w;
      }
      #pragma unroll
      for(int k1 = 0; k1 < 3; ++k1){
        #pragma unroll
        for(int k2 = 0; k2 < 3; ++k2){
          float wv = wb[k1 * 3 + k2];
          #pragma unroll
          for(int j = 0; j < 4; ++j) acc[co][j] += wv * pr[k1][k2 + j];
        }
      }
    }
  }
  #pragma unroll
  for(int co = 0; co < CO; ++co){
    TO* po = out + (size_t)((co * 32 + h) * 32 + w) * 1024 + tid * 4;
    float4 r;
    r.x = fmaxf(acc[co][0], 0.f); r.y = fmaxf(acc[co][1], 0.f);
    r.z = fmaxf(acc[co][2], 0.f); r.w = fmaxf(acc[co][3], 0.f);
    if(ACCUM){
      float4 p0 = ld4(po);
      r.x += p0.x; r.y += p0.y; r.z += p0.z; r.w += p0.w;
    }
    st4(po, r);
  }
}

// ---------- mm2 + mask + softmax fused, one block per (b,q) row ----------
__global__ __launch_bounds__(256) void softmax_k(
    const float* __restrict__ y, const float* __restrict__ rmax,
    const unsigned* __restrict__ cbits, const void* __restrict__ mask,
    const int* __restrict__ mode, float* __restrict__ attn){
  int row = blockIdx.x;          // b*1024+q
  int b = row >> 10;
  int tid = threadIdx.x;
  int kc = tid * 4;
  float ra = rmax[row] + EPSF;
  float4 v = *(const float4*)(y + (size_t)row * 1024 + kc);
  int md = *mode;
  float vv[4] = {v.x, v.y, v.z, v.w};
  float s[4];
  #pragma unroll
  for(int j = 0; j < 4; ++j){
    int k = kc + j;
    float cb = fdec(cbits[(b << 10) + k]) + EPSF;
    float m = vv[j] * vv[j] * vv[j] / (ra * cb);
    bool msk;
    if(md == 0)      msk = ((const int*)mask)[(b << 10) + k] != 0;
    else if(md == 1) msk = ((const float*)mask)[(b << 10) + k] != 0.f;
    else             msk = ((const unsigned char*)mask)[(b << 10) + k] != 0;
    if(msk) m = 1e-4f;
    s[j] = m * TEMPF;
  }
  float mx = fmaxf(fmaxf(s[0], s[1]), fmaxf(s[2], s[3]));
  mx = blockMax256(mx);
  float e[4]; float sum = 0.f;
  #pragma unroll
  for(int j = 0; j < 4; ++j){ e[j] = expf(s[j] - mx); sum += e[j]; }
  sum = blockSum256(sum);
  float inv = 1.0f / sum;
  float4 o; o.x = e[0] * inv; o.y = e[1] * inv; o.z = e[2] * inv; o.w = e[3] * inv;
  *(float4*)(attn + (size_t)row * 1024 + kc) = o;
}

// ---------- out[b,c,q] = sum_k v[b,c,k] * attn[b,q,k]  (A·B^T, 64x64 tiles) ----------
__global__ __launch_bounds__(256) void bmm_k(const float* __restrict__ v,
    const float* __restrict__ attn, float* __restrict__ out){
  __shared__ float At[64][68];
  __shared__ float Bt[64][68];
  int b = blockIdx.y;
  int ct = blockIdx.x >> 4, qt = blockIdx.x & 15;
  int tid = threadIdx.x;
  int c0 = ct * 64, q0 = qt * 64;
  int tx = tid & 15, ty = tid >> 4;
  float acc[4][4] = {};
  for(int k0 = 0; k0 < 1024; k0 += 64){
    #pragma unroll
    for(int l = 0; l < 4; ++l){
      int r = (tid >> 4) + l * 16;
      int cc = (tid & 15) * 4;
      *(float4*)&At[r][cc] = *(const float4*)(v    + ((size_t)b * 256  + c0 + r) * 1024 + k0 + cc);
      *(float4*)&Bt[r][cc] = *(const float4*)(attn + ((size_t)b * 1024 + q0 + r) * 1024 + k0 + cc);
    }
    __syncthreads();
    for(int kk = 0; kk < 64; ++kk){
      float a_[4], b_[4];
      #pragma unroll
      for(int i = 0; i < 4; ++i){ a_[i] = At[ty * 4 + i][kk]; b_[i] = Bt[tx * 4 + i][kk]; }
      #pragma unroll
      for(int i = 0; i < 4; ++i)
        #pragma unroll
        for(int j = 0; j < 4; ++j) acc[i][j] += a_[i] * b_[j];
    }
    __syncthreads();
  }
  #pragma unroll
  for(int i = 0; i < 4; ++i){
    float4 r; r.x = acc[i][0]; r.y = acc[i][1]; r.z = acc[i][2]; r.w = acc[i][3];
    *(float4*)(out + ((size_t)b * 256 + c0 + ty * 4 + i) * 1024 + q0 + tx * 4) = r;
  }
}

extern "C" void kernel_launch(void* const* d_in, const int* in_sizes, int n_in,
                              void* d_out, int out_size, void* d_ws, size_t ws_size,
                              hipStream_t stream){
  (void)in_sizes; (void)n_in; (void)out_size;
  const float* corr = (const float*)d_in[0];
  const float* v    = (const float*)d_in[1];
  const void*  mask = d_in[2];
  const float* wq[3]  = {(const float*)d_in[3],  (const float*)d_in[7],  (const float*)d_in[11]};
  const float* bq[3]  = {(const float*)d_in[4],  (const float*)d_in[8],  (const float*)d_in[12]};
  const float* wsp[3] = {(const float*)d_in[5],  (const float*)d_in[9],  (const float*)d_in[13]};
  const float* bsp[3] = {(const float*)d_in[6],  (const float*)d_in[10], (const float*)d_in[14]};
  float* out = (float*)d_out;

  // ---- workspace layout (per-batch conv intermediates) ----
  // [x0: 16 MiB f32][y: 16 MiB f32][aux: 128 KiB][t1][t2]
  char* ws = (char*)d_ws;
  const size_t X0_OFF  = 0;
  const size_t Y_OFF   = 16777216;
  const size_t AUX_OFF = 33554432;
  const size_t T_OFF   = 33554432 + 131072;
  const size_t NEED_F32 = T_OFF + 2ull * 10 * 1024 * 1024 * 4;  // ~117.6 MB
  const bool f32tier = ws_size >= NEED_F32;

  float* x0 = (float*)(ws + X0_OFF);
  float* y  = (float*)(ws + Y_OFF);
  float* attn = x0;                    // x0 dead once all conv L0s have run
  char* aux = ws + AUX_OFF;
  float*    rmax1 = (float*)(aux);
  unsigned* cb1   = (unsigned*)(aux + 16384);
  float*    rmax2 = (float*)(aux + 32768);
  unsigned* cb2   = (unsigned*)(aux + 49152);
  int*      flag  = (int*)(aux + 65536);
  const size_t SZ_T = (size_t)10 * 1024 * 1024 * (f32tier ? 4 : 2);
  char* t1 = ws + T_OFF;
  char* t2 = ws + T_OFF + SZ_T;

  detect_k<<<1, 256, 0, stream>>>((const unsigned*)mask, flag);
  zero_k<<<16, 256, 0, stream>>>(cb1, cb2);
  rowmax_k<<<4096, 256, 0, stream>>>(corr, rmax1);
  colmax_k<<<128, 256, 0, stream>>>(corr, cb1);
  mmapply_k<<<4096, 256, 0, stream>>>(corr, rmax1, cb1, x0);

  for(int bb = 0; bb < 4; ++bb){
    const float* xb = x0 + (size_t)bb * 1048576;
    float*       yb = y  + (size_t)bb * 1048576;
    if(f32tier){
      float* T1 = (float*)t1; float* T2 = (float*)t2;
      // path 1: query-weights on (h,w), support-weights on (hs,ws)
      conv_k<1, 10, false, float, float><<<1024, 256, 0, stream>>>(xb, T1, wq[0], bq[0], wsp[0], bsp[0]);
      conv_k<10,10, false, float, float><<<1024, 256, 0, stream>>>(T1, T2, wq[1], bq[1], wsp[1], bsp[1]);
      conv_k<10, 1, false, float, float><<<1024, 256, 0, stream>>>(T2, yb, wq[2], bq[2], wsp[2], bsp[2]);
      // path 2 (symmetric mode): identical stack with weight roles swapped
      conv_k<1, 10, false, float, float><<<1024, 256, 0, stream>>>(xb, T1, wsp[0], bsp[0], wq[0], bq[0]);
      conv_k<10,10, false, float, float><<<1024, 256, 0, stream>>>(T1, T2, wsp[1], bsp[1], wq[1], bq[1]);
      conv_k<10, 1, true , float, float><<<1024, 256, 0, stream>>>(T2, yb, wsp[2], bsp[2], wq[2], bq[2]);
    } else {
      __hip_bfloat16* T1 = (__hip_bfloat16*)t1; __hip_bfloat16* T2 = (__hip_bfloat16*)t2;
      conv_k<1, 10, false, float,          __hip_bfloat16><<<1024, 256, 0, stream>>>(xb, T1, wq[0], bq[0], wsp[0], bsp[0]);
      conv_k<10,10, false, __hip_bfloat16, __hip_bfloat16><<<1024, 256, 0, stream>>>(T1, T2, wq[1], bq[1], wsp[1], bsp[1]);
      conv_k<10, 1, false, __hip_bfloat16, float         ><<<1024, 256, 0, stream>>>(T2, yb, wq[2], bq[2], wsp[2], bsp[2]);
      conv_k<1, 10, false, float,          __hip_bfloat16><<<1024, 256, 0, stream>>>(xb, T1, wsp[0], bsp[0], wq[0], bq[0]);
      conv_k<10,10, false, __hip_bfloat16, __hip_bfloat16><<<1024, 256, 0, stream>>>(T1, T2, wsp[1], bsp[1], wq[1], bq[1]);
      conv_k<10, 1, true , __hip_bfloat16, float         ><<<1024, 256, 0, stream>>>(T2, yb, wsp[2], bsp[2], wq[2], bq[2]);
    }
  }

  rowmax_k<<<4096, 256, 0, stream>>>(y, rmax2);
  colmax_k<<<128, 256, 0, stream>>>(y, cb2);
  softmax_k<<<4096, 256, 0, stream>>>(y, rmax2, cb2, mask, flag, attn);
  bmm_k<<<dim3(64, 4), 256, 0, stream>>>(v, attn, out);
}

// Round 3
// 813.427 us; speedup vs baseline: 1.1904x; 1.1904x over previous
//
#include <hip/hip_runtime.h>
#include <hip/hip_bf16.h>
#include <cstdint>

#define TEMPF 3.0f
#define EPSF 1e-5f

// ---------- ordered-uint float encoding for atomic max ----------
static __device__ __forceinline__ unsigned fkey(float f){
  unsigned u = __float_as_uint(f);
  return (u & 0x80000000u) ? ~u : (u | 0x80000000u);
}
static __device__ __forceinline__ float fdec(unsigned k){
  return (k & 0x80000000u) ? __uint_as_float(k ^ 0x80000000u) : __uint_as_float(~k);
}

__device__ __forceinline__ float blockMax256(float v){
  __shared__ float red[4];
  #pragma unroll
  for(int off = 32; off; off >>= 1) v = fmaxf(v, __shfl_down(v, off));
  __syncthreads();
  if((threadIdx.x & 63) == 0) red[threadIdx.x >> 6] = v;
  __syncthreads();
  return fmaxf(fmaxf(red[0], red[1]), fmaxf(red[2], red[3]));
}
__device__ __forceinline__ float blockSum256(float v){
  __shared__ float red2[4];
  #pragma unroll
  for(int off = 32; off; off >>= 1) v += __shfl_down(v, off);
  __syncthreads();
  if((threadIdx.x & 63) == 0) red2[threadIdx.x >> 6] = v;
  __syncthreads();
  return red2[0] + red2[1] + red2[2] + red2[3];
}

// ---------- mask dtype detection (bool may arrive as u8 / i32 / f32) ----------
__global__ void detect_k(const unsigned* __restrict__ m, int* __restrict__ flag){
  __shared__ int sa, sb;
  int tid = threadIdx.x;
  if(tid == 0){ sa = 0; sb = 0; }
  __syncthreads();
  int a = 0, b2 = 0;
  for(int i = tid; i < 1024; i += 256){
    unsigned w = m[i];
    if(w != 0u && w != 1u) a = 1;
    if(w != 0u && w != 0x3f800000u) b2 = 1;
  }
  if(a)  atomicOr(&sa, 1);
  if(b2) atomicOr(&sb, 1);
  __syncthreads();
  if(tid == 0) *flag = (sa == 0) ? 0 : ((sb == 0) ? 1 : 2);  // 0=int32 1=f32 2=u8
}

__global__ void zero_k(unsigned* a, unsigned* b){
  int i = blockIdx.x * 256 + threadIdx.x;
  if(i < 4096){ a[i] = 0u; b[i] = 0u; }
}

// ---------- row max over 1024-wide rows ----------
__global__ __launch_bounds__(256) void rowmax_k(const float* __restrict__ x,
                                                float* __restrict__ rmax){
  int row = blockIdx.x;
  float4 v = *(const float4*)(x + (size_t)row * 1024 + threadIdx.x * 4);
  float m = fmaxf(fmaxf(v.x, v.y), fmaxf(v.z, v.w));
  m = blockMax256(m);
  if(threadIdx.x == 0) rmax[row] = m;
}

// ---------- col max via ordered-uint atomics ----------
__global__ __launch_bounds__(256) void colmax_k(const float* __restrict__ x,
                                                unsigned* __restrict__ cbits){
  int blk = blockIdx.x;                       // B*32 blocks, 32 rows each
  int b = blk >> 5, rg = blk & 31;
  const float* base = x + (size_t)b * 1024 * 1024 + (size_t)rg * 32 * 1024;
  int col = threadIdx.x * 4;
  float4 m = make_float4(-1e30f, -1e30f, -1e30f, -1e30f);
  for(int r = 0; r < 32; ++r){
    float4 v = *(const float4*)(base + r * 1024 + col);
    m.x = fmaxf(m.x, v.x); m.y = fmaxf(m.y, v.y);
    m.z = fmaxf(m.z, v.z); m.w = fmaxf(m.w, v.w);
  }
  unsigned* cb = cbits + (b << 10) + col;
  atomicMax(cb + 0, fkey(m.x)); atomicMax(cb + 1, fkey(m.y));
  atomicMax(cb + 2, fkey(m.z)); atomicMax(cb + 3, fkey(m.w));
}

// ---------- mutual matching elementwise: c^3 / ((rmax+eps)(cmax+eps)) ----------
__global__ __launch_bounds__(256) void mmapply_k(const float* __restrict__ x,
    const float* __restrict__ rmax, const unsigned* __restrict__ cbits,
    float* __restrict__ out){
  int idx4 = blockIdx.x * 256 + threadIdx.x;
  int b = idx4 >> 18;
  int rem = idx4 & 262143;
  int q = rem >> 8;
  int k = (rem & 255) * 4;
  float4 v = ((const float4*)x)[idx4];
  float ra = rmax[(b << 10) + q] + EPSF;
  const unsigned* cb = cbits + (b << 10) + k;
  float4 o;
  o.x = v.x * v.x * v.x / (ra * (fdec(cb[0]) + EPSF));
  o.y = v.y * v.y * v.y / (ra * (fdec(cb[1]) + EPSF));
  o.z = v.z * v.z * v.z / (ra * (fdec(cb[2]) + EPSF));
  o.w = v.w * v.w * v.w / (ra * (fdec(cb[3]) + EPSF));
  ((float4*)out)[idx4] = o;
}

// ---------- fused CenterPivotConv4d layer (one batch, one path) ----------
// Block = 128 threads = one (h,w) x one 16-row strip of (hs,ws) (512 positions,
// float4 per thread). Grid = 2048. LDS tile 18x36 with zero halos prebuilt:
// interior rows come from the thread's own center load (ds_write_b128), only one
// real boundary row per strip is loaded separately. MODE 0 = relu-write,
// MODE 1 = relu + accumulate into out (second path's last layer).
template<int CI, int CO, int MODE>
__global__ __launch_bounds__(128, 4) void conv_k(
    const float* __restrict__ in, float* __restrict__ out,
    const float* __restrict__ wA, const float* __restrict__ bA,
    const float* __restrict__ wB, const float* __restrict__ bB){
  __shared__ float P[18][36];
  const int tid = threadIdx.x;
  const int blk = blockIdx.x;           // hw*2 + strip (strips adjacent for L2 reuse)
  const int strip = blk & 1;
  const int hw = blk >> 1;
  const int w = hw & 31, h = hw >> 5;
  const int lr = tid >> 3;              // local s-row 0..15
  const int c  = (tid & 7) * 4;         // s-col 0..28
  const int own = hw * 1024 + strip * 512 + tid * 4;   // == + lr*32 + c
  const int halo_src = hw * 1024 + (strip ? 15 * 32 : 16 * 32) + (tid & 7) * 4;
  const int hrow = strip ? 0 : 17;

  // neighbor (h,w) offsets, compile-time deltas; validity per block
  bool valid[9];
  #pragma unroll
  for(int dh = 0; dh < 3; ++dh)
    #pragma unroll
    for(int dw = 0; dw < 3; ++dw)
      valid[dh * 3 + dw] = ((unsigned)(h + dh - 1) < 32u) && ((unsigned)(w + dw - 1) < 32u);

  // zero the whole tile once (halos stay zero forever)
  for(int i = tid; i < 18 * 36; i += 128) ((float*)P)[i] = 0.f;

  float acc[CO][4];
  #pragma unroll
  for(int co = 0; co < CO; ++co){
    float bv = bA[co] + bB[co];
    acc[co][0] = bv; acc[co][1] = bv; acc[co][2] = bv; acc[co][3] = bv;
  }

  for(int ci = 0; ci < CI; ++ci){
    const float* base = in + ci * 1048576 + own;
    float4 qv[9];
    #pragma unroll
    for(int dh = 0; dh < 3; ++dh){
      #pragma unroll
      for(int dw = 0; dw < 3; ++dw){
        const int t = dh * 3 + dw;
        float4 vv = make_float4(0.f, 0.f, 0.f, 0.f);
        if(valid[t]) vv = *(const float4*)(base + ((dh - 1) * 32 + (dw - 1)) * 1024);
        qv[t] = vv;
      }
    }
    float4 hv = make_float4(0.f, 0.f, 0.f, 0.f);
    if(tid < 8) hv = *(const float4*)(in + ci * 1048576 + halo_src);

    __syncthreads();                       // previous tile's readers done (also covers zero-init)
    *(float4*)&P[1 + lr][c] = qv[4];       // interior = own center data
    if(tid < 8) *(float4*)&P[hrow][tid * 4] = hv;
    __syncthreads();                       // tile ready

    float pr[3][6];
    #pragma unroll
    for(int k1 = 0; k1 < 3; ++k1){
      const float* row = &P[lr + k1][0];
      float4 mid = *(const float4*)(row + c);
      pr[k1][0] = row[c == 0 ? 32 : c - 1];   // col 32 is always zero (SAME pad)
      pr[k1][1] = mid.x; pr[k1][2] = mid.y; pr[k1][3] = mid.z; pr[k1][4] = mid.w;
      pr[k1][5] = row[c + 4];                 // c+4 <= 32, col 32 zero
    }

    #pragma unroll
    for(int co = 0; co < CO; ++co){
      const float* wa = wA + (co * CI + ci) * 9;
      const float* wb = wB + (co * CI + ci) * 9;
      #pragma unroll
      for(int t = 0; t < 9; ++t){
        float wv = wa[t];
        acc[co][0] += wv * qv[t].x; acc[co][1] += wv * qv[t].y;
        acc[co][2] += wv * qv[t].z; acc[co][3] += wv * qv[t].w;
      }
      #pragma unroll
      for(int k1 = 0; k1 < 3; ++k1){
        #pragma unroll
        for(int k2 = 0; k2 < 3; ++k2){
          float wv = wb[k1 * 3 + k2];
          #pragma unroll
          for(int j = 0; j < 4; ++j) acc[co][j] += wv * pr[k1][k2 + j];
        }
      }
    }
  }

  #pragma unroll
  for(int co = 0; co < CO; ++co){
    float* po = out + co * 1048576 + own;
    float4 r;
    r.x = fmaxf(acc[co][0], 0.f); r.y = fmaxf(acc[co][1], 0.f);
    r.z = fmaxf(acc[co][2], 0.f); r.w = fmaxf(acc[co][3], 0.f);
    if(MODE == 1){
      float4 p0 = *(const float4*)po;
      r.x += p0.x; r.y += p0.y; r.z += p0.z; r.w += p0.w;
    }
    *(float4*)po = r;
  }
}

// ---------- mm2 + mask + softmax fused, one block per (b,q) row ----------
__global__ __launch_bounds__(256) void softmax_k(
    const float* __restrict__ y, const float* __restrict__ rmax,
    const unsigned* __restrict__ cbits, const void* __restrict__ mask,
    const int* __restrict__ mode, float* __restrict__ attn){
  int row = blockIdx.x;          // b*1024+q
  int b = row >> 10;
  int tid = threadIdx.x;
  int kc = tid * 4;
  float ra = rmax[row] + EPSF;
  float4 v = *(const float4*)(y + (size_t)row * 1024 + kc);
  int md = *mode;
  float vv[4] = {v.x, v.y, v.z, v.w};
  float s[4];
  #pragma unroll
  for(int j = 0; j < 4; ++j){
    int k = kc + j;
    float cb = fdec(cbits[(b << 10) + k]) + EPSF;
    float m = vv[j] * vv[j] * vv[j] / (ra * cb);
    bool msk;
    if(md == 0)      msk = ((const int*)mask)[(b << 10) + k] != 0;
    else if(md == 1) msk = ((const float*)mask)[(b << 10) + k] != 0.f;
    else             msk = ((const unsigned char*)mask)[(b << 10) + k] != 0;
    if(msk) m = 1e-4f;
    s[j] = m * TEMPF;
  }
  float mx = fmaxf(fmaxf(s[0], s[1]), fmaxf(s[2], s[3]));
  mx = blockMax256(mx);
  float e[4]; float sum = 0.f;
  #pragma unroll
  for(int j = 0; j < 4; ++j){ e[j] = expf(s[j] - mx); sum += e[j]; }
  sum = blockSum256(sum);
  float inv = 1.0f / sum;
  float4 o; o.x = e[0] * inv; o.y = e[1] * inv; o.z = e[2] * inv; o.w = e[3] * inv;
  *(float4*)(attn + (size_t)row * 1024 + kc) = o;
}

// ---------- partial[ks][b,c,q] = sum_{k in split ks} v[b,c,k]*attn[b,q,k] ----------
__global__ __launch_bounds__(256) void bmm_k(const float* __restrict__ v,
    const float* __restrict__ attn, float* __restrict__ part){
  __shared__ float At[64][68];
  __shared__ float Bt[64][68];
  int b  = blockIdx.y >> 2;
  int ks = blockIdx.y & 3;
  int ct = blockIdx.x >> 4, qt = blockIdx.x & 15;
  int tid = threadIdx.x;
  int c0 = ct * 64, q0 = qt * 64;
  int tx = tid & 15, ty = tid >> 4;
  float acc[4][4] = {};
  for(int k0 = ks * 256; k0 < ks * 256 + 256; k0 += 64){
    #pragma unroll
    for(int l = 0; l < 4; ++l){
      int r = (tid >> 4) + l * 16;
      int cc = (tid & 15) * 4;
      *(float4*)&At[r][cc] = *(const float4*)(v    + ((size_t)b * 256  + c0 + r) * 1024 + k0 + cc);
      *(float4*)&Bt[r][cc] = *(const float4*)(attn + ((size_t)b * 1024 + q0 + r) * 1024 + k0 + cc);
    }
    __syncthreads();
    #pragma unroll 4
    for(int kk = 0; kk < 64; ++kk){
      float a_[4], b_[4];
      #pragma unroll
      for(int i = 0; i < 4; ++i){ a_[i] = At[ty * 4 + i][kk]; b_[i] = Bt[tx * 4 + i][kk]; }
      #pragma unroll
      for(int i = 0; i < 4; ++i)
        #pragma unroll
        for(int j = 0; j < 4; ++j) acc[i][j] += a_[i] * b_[j];
    }
    __syncthreads();
  }
  float* pb = part + (size_t)ks * 1048576;
  #pragma unroll
  for(int i = 0; i < 4; ++i){
    float4 r; r.x = acc[i][0]; r.y = acc[i][1]; r.z = acc[i][2]; r.w = acc[i][3];
    *(float4*)(pb + ((size_t)b * 256 + c0 + ty * 4 + i) * 1024 + q0 + tx * 4) = r;
  }
}

__global__ __launch_bounds__(256) void bmmred_k(const float* __restrict__ part,
                                                float* __restrict__ out){
  int i = blockIdx.x * 256 + threadIdx.x;      // over 262144 float4
  const float4* p = (const float4*)part;
  float4 a = p[i], b = p[i + 262144], cc = p[i + 524288], d = p[i + 786432];
  float4 o;
  o.x = a.x + b.x + cc.x + d.x;
  o.y = a.y + b.y + cc.y + d.y;
  o.z = a.z + b.z + cc.z + d.z;
  o.w = a.w + b.w + cc.w + d.w;
  ((float4*)out)[i] = o;
}

extern "C" void kernel_launch(void* const* d_in, const int* in_sizes, int n_in,
                              void* d_out, int out_size, void* d_ws, size_t ws_size,
                              hipStream_t stream){
  (void)in_sizes; (void)n_in; (void)out_size; (void)ws_size;
  const float* corr = (const float*)d_in[0];
  const float* v    = (const float*)d_in[1];
  const void*  mask = d_in[2];
  const float* wq[3]  = {(const float*)d_in[3],  (const float*)d_in[7],  (const float*)d_in[11]};
  const float* bq[3]  = {(const float*)d_in[4],  (const float*)d_in[8],  (const float*)d_in[12]};
  const float* wsp[3] = {(const float*)d_in[5],  (const float*)d_in[9],  (const float*)d_in[13]};
  const float* bsp[3] = {(const float*)d_in[6],  (const float*)d_in[10], (const float*)d_in[14]};
  float* out = (float*)d_out;

  // ---- workspace layout (117,571,584 B total — proven fit in round 2) ----
  char* ws = (char*)d_ws;
  float* x0 = (float*)(ws);                      // 16.78 MB
  float* y  = (float*)(ws + 16777216);           // 16.78 MB
  char* aux = ws + 33554432;                     // 128 KiB
  float*    rmax1 = (float*)(aux);
  unsigned* cb1   = (unsigned*)(aux + 16384);
  float*    rmax2 = (float*)(aux + 32768);
  unsigned* cb2   = (unsigned*)(aux + 49152);
  int*      flag  = (int*)(aux + 65536);
  float* t1 = (float*)(ws + 33685504);           // 41.94 MB (10ch, 1 batch)
  float* t2 = (float*)(ws + 75628544);           // 41.94 MB
  float* attn = x0;                              // x0 dead after conv L0s
  float* part = t1;                              // t1 dead before bmm (16.78 MB used)

  detect_k<<<1, 256, 0, stream>>>((const unsigned*)mask, flag);
  zero_k<<<16, 256, 0, stream>>>(cb1, cb2);
  rowmax_k<<<4096, 256, 0, stream>>>(corr, rmax1);
  colmax_k<<<128, 256, 0, stream>>>(corr, cb1);
  mmapply_k<<<4096, 256, 0, stream>>>(corr, rmax1, cb1, x0);

  for(int bb = 0; bb < 4; ++bb){
    const float* xb = x0 + (size_t)bb * 1048576;
    float*       yb = y  + (size_t)bb * 1048576;
    // path 1: query-weights on (h,w), support-weights on (hs,ws)
    conv_k<1, 10, 0><<<2048, 128, 0, stream>>>(xb, t1, wq[0], bq[0], wsp[0], bsp[0]);
    conv_k<10,10, 0><<<2048, 128, 0, stream>>>(t1, t2, wq[1], bq[1], wsp[1], bsp[1]);
    conv_k<10, 1, 0><<<2048, 128, 0, stream>>>(t2, yb, wq[2], bq[2], wsp[2], bsp[2]);
    // path 2 (symmetric mode): identical stack with weight roles swapped
    conv_k<1, 10, 0><<<2048, 128, 0, stream>>>(xb, t1, wsp[0], bsp[0], wq[0], bq[0]);
    conv_k<10,10, 0><<<2048, 128, 0, stream>>>(t1, t2, wsp[1], bsp[1], wq[1], bq[1]);
    conv_k<10, 1, 1><<<2048, 128, 0, stream>>>(t2, yb, wsp[2], bsp[2], wq[2], bq[2]);
  }

  rowmax_k<<<4096, 256, 0, stream>>>(y, rmax2);
  colmax_k<<<128, 256, 0, stream>>>(y, cb2);
  softmax_k<<<4096, 256, 0, stream>>>(y, rmax2, cb2, mask, flag, attn);
  bmm_k<<<dim3(64, 16), 256, 0, stream>>>(v, attn, part);
  bmmred_k<<<1024, 256, 0, stream>>>(part, out);
}